// Round 14
// baseline (36.800 us; speedup 1.0000x reference)
//
#include <hip/hip_runtime.h>
#include <hip/hip_bf16.h>
#include <stdint.h>

// SVR polynomial-kernel prediction:
//   out[m] = sum_n alpha[n] * (1 + x_p[m].X[n])^4 + b
// m=16384, n=8192, d=64, all fp32 in/out.
// R14 = R10 (passing, 34.0us) with ONE change: 32x32x16 bf16 MFMA
//   (m119: +15% pipe rate, halves MFMA instruction count 16->8/wave/chunk).
//   C/D layout (verified m74/m101): col=lane&31, row=(reg&3)+8*(reg>>2)+4*(lane>>5).
//   A/B layout (B^T convention): row/col=lane&31, k=ks*16+(lane>>5)*8+j.
//   Xs pre-swizzle unchanged: slot=(k>>3)^(n&7) -- new reads still match.
// R13 lesson: NO inline-asm VALU (v_pk_* op_sel hazard); plain scalar epilogue.
// Kept verbatim: NSPLIT=4 (512 blocks = 2/CU), dbuf LDS + gll16 linear
// staging (rule 21), a4-prescaled Xs + a4 C-init, ping-pong deferred
// epilogue, alpha prefetch, partials+finalize (no atomics).

typedef __attribute__((ext_vector_type(8))) short bf16x8;
typedef __attribute__((ext_vector_type(8))) unsigned short ushort8;
typedef __attribute__((ext_vector_type(16))) float f32x16;

#define MM 16384
#define NN 8192
#define DD 64
#define NSPLIT 4           // n-splits -> partial slices
#define CHUNK 64           // n-cols per LDS chunk
#define CHUNKS_PER_BLK 32  // 8192 / (4*64)
#define BM 128             // m-rows per block

__device__ __forceinline__ unsigned short f2bf(float f) {
    uint32_t u = __float_as_uint(f);
    uint32_t r = (u + 0x7FFFu + ((u >> 16) & 1u)) >> 16;  // RNE
    return (unsigned short)r;
}

__device__ __forceinline__ void gll16(const void* g, void* l) {
    __builtin_amdgcn_global_load_lds(
        (const __attribute__((address_space(1))) unsigned int*)g,
        (__attribute__((address_space(3))) unsigned int*)l, 16, 0, 0);
}

// xp -> xbf linear row-major [16384][64] bf16.
// X  -> Xs swizzled: element (n,k) at shorts:
//   (n>>6)*4096 + (n&63)*64 + ((k>>3) ^ (n&7))*8 + (k&7),  prescaled by a4[n].
// alpha4f[n] = alpha[n]^(1/4).
__global__ void convert_kernel(const float* __restrict__ xp,
                               const float* __restrict__ X,
                               const float* __restrict__ alpha,
                               unsigned short* __restrict__ xbf,
                               unsigned short* __restrict__ Xs,
                               float* __restrict__ alpha4f) {
    const int xp4 = MM * DD / 4;          // 262144 float4 units
    const int xu = NN * DD / 8;           // 65536 16B units
    const int tot = xp4 + xu;
    int tid0 = blockIdx.x * blockDim.x + threadIdx.x;
    if (tid0 < NN) alpha4f[tid0] = sqrtf(sqrtf(alpha[tid0]));
    int stride = gridDim.x * blockDim.x;
    for (int i = tid0; i < tot; i += stride) {
        if (i < xp4) {
            float4 v = ((const float4*)xp)[i];
            ushort4 o;
            o.x = f2bf(v.x); o.y = f2bf(v.y); o.z = f2bf(v.z); o.w = f2bf(v.w);
            *(ushort4*)(xbf + (size_t)i * 4) = o;
        } else {
            int u = i - xp4;
            int n = u >> 3;
            int slot = u & 7;
            float a4 = sqrtf(sqrtf(alpha[n]));
            float4 va = ((const float4*)X)[n * 16 + slot * 2];
            float4 vb = ((const float4*)X)[n * 16 + slot * 2 + 1];
            ushort8 o;
            o[0] = f2bf(va.x * a4); o[1] = f2bf(va.y * a4);
            o[2] = f2bf(va.z * a4); o[3] = f2bf(va.w * a4);
            o[4] = f2bf(vb.x * a4); o[5] = f2bf(vb.y * a4);
            o[6] = f2bf(vb.z * a4); o[7] = f2bf(vb.w * a4);
            size_t dst = (size_t)(n >> 6) * 4096 + (n & 63) * 64
                       + ((slot ^ (n & 7)) * 8);
            *(ushort8*)(Xs + dst) = o;
        }
    }
}

// Stage block-local chunk CLOC into LDS buffer (CLOC&1)
#define STAGE(CLOC)                                                   \
    {                                                                 \
        const char* gs = (const char*)Xs                              \
            + (size_t)(chunk0 + (CLOC)) * 8192 + tid * 16;            \
        char* lb = smem + ((CLOC) & 1) * 8192 + w * 1024;             \
        gll16(gs, lb);                                                \
        gll16(gs + 4096, lb + 4096);                                  \
    }

// Consume chunk CLOC: 8 ds_read + 8 MFMA into ACC_THIS (C-init av_c),
// deferred epilogue of ACC_PREV. Stages CLOC+1 first; barrier at end.
#define DO_CHUNK(CLOC, ACC_THIS, ACC_PREV, DOPREV)                    \
    {                                                                 \
        float av_n[2];                                                \
        if ((CLOC) + 1 < CHUNKS_PER_BLK) {                            \
            STAGE((CLOC) + 1);                                        \
            _Pragma("unroll")                                         \
            for (int nt = 0; nt < 2; ++nt)                            \
                av_n[nt] = alpha4f[(chunk0 + (CLOC) + 1) * CHUNK      \
                                   + nt * 32 + nl];                   \
        }                                                             \
        const char* buf = smem + ((CLOC) & 1) * 8192;                 \
        bf16x8 bfr[2][4];                                             \
        _Pragma("unroll")                                             \
        for (int nt = 0; nt < 2; ++nt) {                              \
            const int n = nt * 32 + nl;                               \
            const char* rowp = buf + n * 128;                         \
            _Pragma("unroll")                                         \
            for (int ks = 0; ks < 4; ++ks) {                          \
                const int slot = (ks * 2 + kh) ^ (n & 7);             \
                bfr[nt][ks] = *(const bf16x8*)(rowp + slot * 16);     \
            }                                                         \
        }                                                             \
        _Pragma("unroll")                                             \
        for (int nt = 0; nt < 2; ++nt) {                              \
            _Pragma("unroll")                                         \
            for (int i = 0; i < 16; ++i) ACC_THIS[nt][i] = av_c[nt];  \
        }                                                             \
        _Pragma("unroll")                                             \
        for (int ks = 0; ks < 4; ++ks)                                \
            _Pragma("unroll")                                         \
            for (int nt = 0; nt < 2; ++nt)                            \
                ACC_THIS[nt] = __builtin_amdgcn_mfma_f32_32x32x16_bf16( \
                    a[ks], bfr[nt][ks], ACC_THIS[nt], 0, 0, 0);       \
        if (DOPREV) {                                                 \
            _Pragma("unroll")                                         \
            for (int nt = 0; nt < 2; ++nt)                            \
                _Pragma("unroll")                                     \
                for (int i = 0; i < 16; ++i) {                        \
                    float t = ACC_PREV[nt][i];                        \
                    float t2 = t * t;                                 \
                    red[i] = fmaf(t2, t2, red[i]);                    \
                }                                                     \
        }                                                             \
        __syncthreads();                                              \
        _Pragma("unroll")                                             \
        for (int nt = 0; nt < 2; ++nt) av_c[nt] = av_n[nt];           \
    }

__global__ __launch_bounds__(256) void svr_main(
        const unsigned short* __restrict__ xbf,
        const unsigned short* __restrict__ Xs,
        const float* __restrict__ alpha4f,
        float* __restrict__ partials) {
    __shared__ char smem[16384];          // 2 x 8KB chunk buffers
    const int tid  = threadIdx.x;
    const int lane = tid & 63;
    const int w    = tid >> 6;            // wave 0..3, owns rows [w*32, w*32+32)
    const int nl   = lane & 31;           // A-row / B-col within 32-tile
    const int kh   = lane >> 5;           // k-half selector
    const int mgroup = blockIdx.x >> 2;   // 0..127
    const int ns     = blockIdx.x & 3;    // 0..3

    // A fragments: 1 m-tile (32 rows) x 4 k-steps, register-resident.
    // 32x32x16 A layout: row = lane&31, k = ks*16 + (lane>>5)*8 + j
    bf16x8 a[4];
#pragma unroll
    for (int ks = 0; ks < 4; ++ks)
        a[ks] = *(const bf16x8*)(
            xbf + (size_t)(mgroup * BM + w * 32 + nl) * DD
                + ks * 16 + kh * 8);

    float red[16];
#pragma unroll
    for (int i = 0; i < 16; ++i) red[i] = 0.f;

    const int chunk0 = ns * CHUNKS_PER_BLK;

    // prologue: stage chunk0; load alpha for chunk0
    STAGE(0);
    float av_c[2];
#pragma unroll
    for (int nt = 0; nt < 2; ++nt)
        av_c[nt] = alpha4f[chunk0 * CHUNK + nt * 32 + nl];
    __syncthreads();

    f32x16 accE[2], accO[2];

#pragma unroll 1
    for (int p = 0; p < CHUNKS_PER_BLK / 2; ++p) {
        DO_CHUNK(2 * p,     accE, accO, (p > 0));
        DO_CHUNK(2 * p + 1, accO, accE, true);
    }
    // trailing epilogue: last chunk's accO
#pragma unroll
    for (int nt = 0; nt < 2; ++nt)
#pragma unroll
        for (int i = 0; i < 16; ++i) {
            float t = accO[nt][i];
            float t2 = t * t;
            red[i] = fmaf(t2, t2, red[i]);
        }

    // reduce across the 32 column-lanes (nl); rows live at
    // (i&3) + 8*(i>>2) + 4*kh per reg i (C/D layout m74/m101)
#pragma unroll
    for (int i = 0; i < 16; ++i) {
        float v = red[i];
        v += __shfl_xor(v, 1);
        v += __shfl_xor(v, 2);
        v += __shfl_xor(v, 4);
        v += __shfl_xor(v, 8);
        v += __shfl_xor(v, 16);
        red[i] = v;
    }
    if (nl == 0) {
#pragma unroll
        for (int i = 0; i < 16; ++i) {
            int row_local = (i & 3) + 8 * (i >> 2) + 4 * kh;
            int row = mgroup * BM + w * 32 + row_local;
            partials[(size_t)ns * MM + row] = red[i];
        }
    }
}

__global__ void finalize_kernel(const float* __restrict__ partials,
                                const float* __restrict__ bbias,
                                float* __restrict__ out) {
    int m = blockIdx.x * blockDim.x + threadIdx.x;
    if (m < MM) {
        float s = bbias[0];
#pragma unroll
        for (int c = 0; c < NSPLIT; ++c) s += partials[(size_t)c * MM + m];
        out[m] = s;
    }
}

extern "C" void kernel_launch(void* const* d_in, const int* in_sizes, int n_in,
                              void* d_out, int out_size, void* d_ws, size_t ws_size,
                              hipStream_t stream) {
    const float* xp    = (const float*)d_in[0];
    const float* X     = (const float*)d_in[1];
    const float* alpha = (const float*)d_in[2];
    const float* b     = (const float*)d_in[3];
    float* out = (float*)d_out;

    // ws: xbf 2MB | Xs 1MB | alpha4f 32KB | partials 4*16384*4 = 256KB
    unsigned short* xbf = (unsigned short*)d_ws;
    unsigned short* Xs  = xbf + (size_t)MM * DD;
    float* alpha4f = (float*)(Xs + (size_t)NN * DD);
    float* partials = alpha4f + NN;

    hipLaunchKernelGGL(convert_kernel, dim3(1280), dim3(256), 0, stream,
                       xp, X, alpha, xbf, Xs, alpha4f);

    hipLaunchKernelGGL(svr_main, dim3(128 * NSPLIT), dim3(256), 0, stream,
                       xbf, Xs, alpha4f, partials);

    hipLaunchKernelGGL(finalize_kernel, dim3(MM / 256), dim3(256), 0, stream,
                       partials, b, out);
}

// Round 15
// 33.001 us; speedup vs baseline: 1.1151x; 1.1151x over previous
//
#include <hip/hip_runtime.h>
#include <hip/hip_bf16.h>
#include <stdint.h>

// SVR polynomial-kernel prediction:
//   out[m] = sum_n alpha[n] * (1 + x_p[m].X[n])^4 + b
// m=16384, n=8192, d=64, all fp32 in/out.
// R15 = R8 skeleton (NSPLIT=8, 1024 blocks = 4/CU -> independent-block
// pipe overlap, m114) + three stacked safe levers:
//   1. __launch_bounds__(256,4): pin 4 blocks/CU residency (VGPR<=128)
//   2. alpha-quad as MFMA C-operand (acc = A.B + cav): deletes 32
//      C-init movs/chunk; C-input holds a4 so acc = a4*(1+x.X) directly
//   3. float2 epilogue (COMPILER-generated v_pk_*, no inline asm -- R13
//      lesson): 96->~48 VALU instr/chunk
//   4. s_setprio(1) around MFMA cluster (T5; independent blocks provide
//      the role diversity the mechanism needs)
// Proven pieces verbatim: pre-swizzled Xs + linear global_load_lds
// (rule 21), swizzled ds_read slot=(bh*4+g)^(rr&7), a4-prescaled Xs,
// alpha prefetched one chunk ahead, partials+finalize (no atomics).

typedef __attribute__((ext_vector_type(8))) short bf16x8;
typedef __attribute__((ext_vector_type(8))) unsigned short ushort8;
typedef __attribute__((ext_vector_type(4))) float f32x4;
typedef __attribute__((ext_vector_type(2))) float f32v2;

#define MM 16384
#define NN 8192
#define DD 64
#define NSPLIT 8           // n-splits -> partial slices
#define CHUNK 64           // n-cols per LDS chunk
#define CHUNKS_PER_BLK 16  // 8192 / (8*64)
#define BM 128             // m-rows per block

__device__ __forceinline__ unsigned short f2bf(float f) {
    uint32_t u = __float_as_uint(f);
    uint32_t r = (u + 0x7FFFu + ((u >> 16) & 1u)) >> 16;  // RNE
    return (unsigned short)r;
}

__device__ __forceinline__ void gll16(const void* g, void* l) {
    __builtin_amdgcn_global_load_lds(
        (const __attribute__((address_space(1))) unsigned int*)g,
        (__attribute__((address_space(3))) unsigned int*)l, 16, 0, 0);
}

// xp -> xbf linear row-major [16384][64] bf16.
// X  -> Xs swizzled: element (n,k) at shorts:
//   (n>>6)*4096 + (n&63)*64 + ((k>>3) ^ (n&7))*8 + (k&7),  prescaled by a4[n].
// alpha4f[n] = alpha[n]^(1/4).
__global__ void convert_kernel(const float* __restrict__ xp,
                               const float* __restrict__ X,
                               const float* __restrict__ alpha,
                               unsigned short* __restrict__ xbf,
                               unsigned short* __restrict__ Xs,
                               float* __restrict__ alpha4f) {
    const int xp4 = MM * DD / 4;          // 262144 float4 units
    const int xu = NN * DD / 8;           // 65536 16B units
    const int tot = xp4 + xu;
    int tid0 = blockIdx.x * blockDim.x + threadIdx.x;
    if (tid0 < NN) alpha4f[tid0] = sqrtf(sqrtf(alpha[tid0]));
    int stride = gridDim.x * blockDim.x;
    for (int i = tid0; i < tot; i += stride) {
        if (i < xp4) {
            float4 v = ((const float4*)xp)[i];
            ushort4 o;
            o.x = f2bf(v.x); o.y = f2bf(v.y); o.z = f2bf(v.z); o.w = f2bf(v.w);
            *(ushort4*)(xbf + (size_t)i * 4) = o;
        } else {
            int u = i - xp4;
            int n = u >> 3;
            int slot = u & 7;
            float a4 = sqrtf(sqrtf(alpha[n]));
            float4 va = ((const float4*)X)[n * 16 + slot * 2];
            float4 vb = ((const float4*)X)[n * 16 + slot * 2 + 1];
            ushort8 o;
            o[0] = f2bf(va.x * a4); o[1] = f2bf(va.y * a4);
            o[2] = f2bf(va.z * a4); o[3] = f2bf(va.w * a4);
            o[4] = f2bf(vb.x * a4); o[5] = f2bf(vb.y * a4);
            o[6] = f2bf(vb.z * a4); o[7] = f2bf(vb.w * a4);
            size_t dst = (size_t)(n >> 6) * 4096 + (n & 63) * 64
                       + ((slot ^ (n & 7)) * 8);
            *(ushort8*)(Xs + dst) = o;
        }
    }
}

__global__ __launch_bounds__(256, 4) void svr_main(
        const unsigned short* __restrict__ xbf,
        const unsigned short* __restrict__ Xs,
        const float* __restrict__ alpha4f,
        float* __restrict__ partials) {
    __shared__ char smem[16384];          // 2 x 8KB chunk buffers
    const int tid  = threadIdx.x;
    const int lane = tid & 63;
    const int w    = tid >> 6;            // wave 0..3, owns rows [w*32, w*32+32)
    const int r    = lane & 15;           // row-in-tile / col-in-tile
    const int g    = lane >> 4;           // k-slice selector
    const int mgroup = blockIdx.x >> 3;   // 0..127
    const int ns     = blockIdx.x & 7;    // 0..7

    // A fragments: 2 m-tiles x 2 k-slices, regs for whole kernel
    bf16x8 a[2][2];
#pragma unroll
    for (int mt = 0; mt < 2; ++mt)
#pragma unroll
        for (int ks = 0; ks < 2; ++ks)
            a[mt][ks] = *(const bf16x8*)(
                xbf + (size_t)(mgroup * BM + w * 32 + mt * 16 + r) * DD
                    + ks * 32 + g * 8);

    // red accumulators as packed float2 pairs: [mt][0]=elems 0,1  [1]=2,3
    f32v2 red2[2][2];
#pragma unroll
    for (int mt = 0; mt < 2; ++mt) {
        red2[mt][0] = (f32v2){0.f, 0.f};
        red2[mt][1] = (f32v2){0.f, 0.f};
    }

    const int chunk0 = ns * CHUNKS_PER_BLK;

    // prologue: stage chunk0 into buf0; load alpha for chunk0
    {
        const char* gs = (const char*)Xs + (size_t)chunk0 * 8192 + tid * 16;
        char* lb = smem + w * 1024;       // wave-uniform base; +lane*16 implicit
        gll16(gs, lb);
        gll16(gs + 4096, lb + 4096);
    }
    float av4[4];
#pragma unroll
    for (int nt = 0; nt < 4; ++nt)
        av4[nt] = alpha4f[chunk0 * CHUNK + nt * 16 + r];
    __syncthreads();

    int cur = 0;
#pragma unroll 1
    for (int c = 0; c < CHUNKS_PER_BLK; ++c) {
        float av4n[4];
        if (c + 1 < CHUNKS_PER_BLK) {      // stage next chunk into other buffer
            const char* gs = (const char*)Xs
                           + (size_t)(chunk0 + c + 1) * 8192 + tid * 16;
            char* lb = smem + (cur ^ 1) * 8192 + w * 1024;
            gll16(gs, lb);
            gll16(gs + 4096, lb + 4096);
#pragma unroll
            for (int nt = 0; nt < 4; ++nt)
                av4n[nt] = alpha4f[(chunk0 + c + 1) * CHUNK + nt * 16 + r];
        }
        // B fragments from swizzled LDS: rr = nt*16+r, slot = (bh*4+g)^(rr&7)
        bf16x8 b[4][2];
#pragma unroll
        for (int nt = 0; nt < 4; ++nt) {
            const int rr = nt * 16 + r;
            const char* rowp = smem + cur * 8192 + rr * 128;
#pragma unroll
            for (int bh = 0; bh < 2; ++bh) {
                const int slot = (bh * 4 + g) ^ (rr & 7);
                b[nt][bh] = *(const bf16x8*)(rowp + slot * 16);
            }
        }
        // C-operand quads: cav[nt] = {a4,a4,a4,a4} (MFMA C-input IS the init)
        f32x4 cav[4];
#pragma unroll
        for (int nt = 0; nt < 4; ++nt)
            cav[nt] = (f32x4){av4[nt], av4[nt], av4[nt], av4[nt]};
        // MFMA cluster under raised priority (T5); acc = a4 + a4*(x.X)
        f32x4 acc[2][4];
        __builtin_amdgcn_s_setprio(1);
#pragma unroll
        for (int nt = 0; nt < 4; ++nt)
#pragma unroll
            for (int mt = 0; mt < 2; ++mt)
                acc[mt][nt] = __builtin_amdgcn_mfma_f32_16x16x32_bf16(
                    a[mt][0], b[nt][0], cav[nt], 0, 0, 0);
#pragma unroll
        for (int nt = 0; nt < 4; ++nt)
#pragma unroll
            for (int mt = 0; mt < 2; ++mt)
                acc[mt][nt] = __builtin_amdgcn_mfma_f32_16x16x32_bf16(
                    a[mt][1], b[nt][1], acc[mt][nt], 0, 0, 0);
        __builtin_amdgcn_s_setprio(0);
        // packed epilogue (compiler-generated v_pk_*): red += (t*t)*(t*t)
#pragma unroll
        for (int mt = 0; mt < 2; ++mt)
#pragma unroll
            for (int nt = 0; nt < 4; ++nt) {
                f32v2 lo = (f32v2){acc[mt][nt][0], acc[mt][nt][1]};
                f32v2 hi = (f32v2){acc[mt][nt][2], acc[mt][nt][3]};
                f32v2 lo2 = lo * lo;
                f32v2 hi2 = hi * hi;
                red2[mt][0] = lo2 * lo2 + red2[mt][0];
                red2[mt][1] = hi2 * hi2 + red2[mt][1];
            }
        __syncthreads();
        cur ^= 1;
        if (c + 1 < CHUNKS_PER_BLK) {
#pragma unroll
            for (int nt = 0; nt < 4; ++nt) av4[nt] = av4n[nt];
        }
    }

    // reduce across the 16 column-lanes (r); rows live at g*4+i per m-tile
#pragma unroll
    for (int mt = 0; mt < 2; ++mt)
#pragma unroll
        for (int i = 0; i < 4; ++i) {
            float v = red2[mt][i >> 1][i & 1];
            v += __shfl_xor(v, 1);
            v += __shfl_xor(v, 2);
            v += __shfl_xor(v, 4);
            v += __shfl_xor(v, 8);
            if (r == 0) {
                int row = mgroup * BM + w * 32 + mt * 16 + g * 4 + i;
                partials[(size_t)ns * MM + row] = v;
            }
        }
}

__global__ void finalize_kernel(const float* __restrict__ partials,
                                const float* __restrict__ bbias,
                                float* __restrict__ out) {
    int m = blockIdx.x * blockDim.x + threadIdx.x;
    if (m < MM) {
        float s = bbias[0];
#pragma unroll
        for (int c = 0; c < NSPLIT; ++c) s += partials[(size_t)c * MM + m];
        out[m] = s;
    }
}

extern "C" void kernel_launch(void* const* d_in, const int* in_sizes, int n_in,
                              void* d_out, int out_size, void* d_ws, size_t ws_size,
                              hipStream_t stream) {
    const float* xp    = (const float*)d_in[0];
    const float* X     = (const float*)d_in[1];
    const float* alpha = (const float*)d_in[2];
    const float* b     = (const float*)d_in[3];
    float* out = (float*)d_out;

    // ws: xbf 2MB | Xs 1MB | alpha4f 32KB | partials 8*16384*4 = 512KB
    unsigned short* xbf = (unsigned short*)d_ws;
    unsigned short* Xs  = xbf + (size_t)MM * DD;
    float* alpha4f = (float*)(Xs + (size_t)NN * DD);
    float* partials = alpha4f + NN;

    hipLaunchKernelGGL(convert_kernel, dim3(1280), dim3(256), 0, stream,
                       xp, X, alpha, xbf, Xs, alpha4f);

    hipLaunchKernelGGL(svr_main, dim3(128 * NSPLIT), dim3(256), 0, stream,
                       xbf, Xs, alpha4f, partials);

    hipLaunchKernelGGL(finalize_kernel, dim3(MM / 256), dim3(256), 0, stream,
                       partials, b, out);
}